// Round 2
// baseline (23.475 us; speedup 1.0000x reference)
//
#include <hip/hip_runtime.h>
#include <math.h>

#define BB 1024
#define DD 128
#define TILE 64

constexpr float EPSF = 1e-6f;
constexpr float MARGINF = 1.0f;
constexpr float INV_COUNT = 1.0f / (float)((BB - 1) * BB);  // 1/1047552

typedef __attribute__((ext_vector_type(8))) short bf16x8;
typedef __attribute__((ext_vector_type(4))) float f32x4;

__device__ __forceinline__ short f2bf(float f) {
    // round-to-nearest-even fp32 -> bf16
    unsigned int u = __builtin_bit_cast(unsigned int, f);
    u += 0x7fffu + ((u >> 16) & 1u);
    return (short)(u >> 16);
}

__device__ __forceinline__ bf16x8 load_frag(const float* __restrict__ p) {
    const float4 v0 = reinterpret_cast<const float4*>(p)[0];
    const float4 v1 = reinterpret_cast<const float4*>(p)[1];
    bf16x8 f;
    f[0] = f2bf(v0.x); f[1] = f2bf(v0.y); f[2] = f2bf(v0.z); f[3] = f2bf(v0.w);
    f[4] = f2bf(v1.x); f[5] = f2bf(v1.y); f[6] = f2bf(v1.z); f[7] = f2bf(v1.w);
    return f;
}

__device__ __forceinline__ float qreduce(float v) {  // reduce over 4-lane quads
    v += __shfl_xor(v, 1);
    v += __shfl_xor(v, 2);
    return v;
}

// One block per 64x64 output tile. 512 threads = 8 waves (2 row-groups x 4
// col-groups of 32x16 sub-tiles). Dot matrix via bf16 MFMA with fragments
// loaded directly from global (L2-resident); exact-fp32 row/col stats
// computed in-block; fused sqrt/relu/reduce epilogue; one atomicAdd.
__global__ __launch_bounds__(512) void triplet_fused_k(const float* __restrict__ a,
                                                       const float* __restrict__ b,
                                                       float* __restrict__ out) {
    __shared__ float ta_s[TILE];   // ||a||^2 + 2*eps*sum(a)   (rows j0..)
    __shared__ float tb_s[TILE];   // ||b||^2 - 2*eps*sum(b)   (cols k0..)
    __shared__ float dap_s[TILE];  // ||a - b + eps||          (rows j0..)
    __shared__ float wsum_s[8];

    const int tid = threadIdx.x;
    const int j0 = (int)blockIdx.y * TILE;
    const int k0 = (int)blockIdx.x * TILE;

    // ---- Phase 1: per-block row/col stats (exact fp32) ----
    {
        const int row = (tid & 255) >> 2;  // 0..63
        const int seg = tid & 3;           // 32 elems each
        if (tid < 256) {
            const float4* pa = reinterpret_cast<const float4*>(
                a + (size_t)(j0 + row) * DD + seg * 32);
            const float4* pb = reinterpret_cast<const float4*>(
                b + (size_t)(j0 + row) * DD + seg * 32);
            float sa2 = 0.f, sa = 0.f, sap = 0.f;
#pragma unroll
            for (int i = 0; i < 8; ++i) {
                const float4 av = pa[i];
                const float4 bv = pb[i];
                const float* af = reinterpret_cast<const float*>(&av);
                const float* bf_ = reinterpret_cast<const float*>(&bv);
#pragma unroll
                for (int c = 0; c < 4; ++c) {
                    const float x = af[c];
                    const float d = x - bf_[c] + EPSF;
                    sa2 = fmaf(x, x, sa2);
                    sa += x;
                    sap = fmaf(d, d, sap);
                }
            }
            sa2 = qreduce(sa2);
            sa  = qreduce(sa);
            sap = qreduce(sap);
            if (seg == 0) {
                ta_s[row]  = fmaf(2.f * EPSF, sa, sa2);
                dap_s[row] = sqrtf(sap);
            }
        } else {
            const float4* pb = reinterpret_cast<const float4*>(
                b + (size_t)(k0 + row) * DD + seg * 32);
            float sb2 = 0.f, sb = 0.f;
#pragma unroll
            for (int i = 0; i < 8; ++i) {
                const float4 bv = pb[i];
                const float* bf_ = reinterpret_cast<const float*>(&bv);
#pragma unroll
                for (int c = 0; c < 4; ++c) {
                    const float x = bf_[c];
                    sb2 = fmaf(x, x, sb2);
                    sb += x;
                }
            }
            sb2 = qreduce(sb2);
            sb  = qreduce(sb);
            if (seg == 0) tb_s[row] = fmaf(-2.f * EPSF, sb, sb2);
        }
    }
    __syncthreads();

    // ---- Phase 2: dot matrix via bf16 MFMA, fragments direct from global ----
    const int w    = tid >> 6;   // wave 0..7
    const int lane = tid & 63;
    const int wr   = w >> 2;     // 0..1 : 32-row group
    const int wc   = w & 3;      // 0..3 : 16-col group
    const int lr   = lane & 15;  // fragment row/col
    const int lk   = lane >> 4;  // k-group (8 elems)

    f32x4 acc[2] = {{0.f, 0.f, 0.f, 0.f}, {0.f, 0.f, 0.f, 0.f}};
    const float* arow0 = a + (size_t)(j0 + wr * 32 + lr) * DD + lk * 8;
    const float* arow1 = arow0 + (size_t)16 * DD;
    const float* brow  = b + (size_t)(k0 + wc * 16 + lr) * DD + lk * 8;

#pragma unroll
    for (int kc = 0; kc < 4; ++kc) {  // K = 128 in chunks of 32
        const bf16x8 af0 = load_frag(arow0 + kc * 32);
        const bf16x8 af1 = load_frag(arow1 + kc * 32);
        const bf16x8 bfr = load_frag(brow + kc * 32);
        acc[0] = __builtin_amdgcn_mfma_f32_16x16x32_bf16(af0, bfr, acc[0], 0, 0, 0);
        acc[1] = __builtin_amdgcn_mfma_f32_16x16x32_bf16(af1, bfr, acc[1], 0, 0, 0);
    }

    // ---- Phase 3: fused epilogue ----
    const float Ceps = (float)DD * EPSF * EPSF;
    const int colL = wc * 16 + lr;
    const int col  = k0 + colL;
    const float tb = tb_s[colL];
    float local = 0.f;
#pragma unroll
    for (int m = 0; m < 2; ++m) {
#pragma unroll
        for (int r = 0; r < 4; ++r) {
            const int rowL = wr * 32 + m * 16 + lk * 4 + r;
            const int row  = j0 + rowL;
            float d2 = ta_s[rowL] + tb + Ceps - 2.f * acc[m][r];
            const float dn = sqrtf(fmaxf(d2, 0.f));
            if (row != col) local += fmaxf(dap_s[rowL] - dn + MARGINF, 0.f);
        }
    }

    // wave reduce (64 lanes) then block reduce (8 waves) then one atomic
#pragma unroll
    for (int off = 32; off >= 1; off >>= 1) local += __shfl_xor(local, off);
    if (lane == 0) wsum_s[w] = local;
    __syncthreads();
    if (tid == 0) {
        float s = 0.f;
#pragma unroll
        for (int i = 0; i < 8; ++i) s += wsum_s[i];
        atomicAdd(out, s * INV_COUNT);
    }
}

extern "C" void kernel_launch(void* const* d_in, const int* in_sizes, int n_in,
                              void* d_out, int out_size, void* d_ws, size_t ws_size,
                              hipStream_t stream) {
    const float* a = (const float*)d_in[0];
    const float* b = (const float*)d_in[1];
    float* out = (float*)d_out;

    // capturable memset node: re-zero the accumulator every replay
    hipMemsetAsync(out, 0, sizeof(float), stream);
    dim3 grid(BB / TILE, BB / TILE);
    triplet_fused_k<<<grid, 512, 0, stream>>>(a, b, out);
}

// Round 3
// 14.533 us; speedup vs baseline: 1.6153x; 1.6153x over previous
//
#include <hip/hip_runtime.h>
#include <math.h>

#define BB 1024
#define DD 128
#define TILE 64
#define NBLK 256  // (BB/TILE)^2 blocks

constexpr float EPSF = 1e-6f;
constexpr float MARGINF = 1.0f;
constexpr float INV_COUNT = 1.0f / (float)((BB - 1) * BB);  // 1/1047552

typedef __attribute__((ext_vector_type(8))) short bf16x8;
typedef __attribute__((ext_vector_type(4))) float f32x4;

union F4 { float4 v; float f[4]; };

__device__ __forceinline__ short f2bf(float f) {
    // round-to-nearest-even fp32 -> bf16
    unsigned int u = __builtin_bit_cast(unsigned int, f);
    u += 0x7fffu + ((u >> 16) & 1u);
    return (short)(u >> 16);
}

// One block per 64x64 output tile; 512 threads = 8 waves (2 row-groups x 4
// col-groups). A/B tiles staged in LDS as bf16 in MFMA-fragment order:
//   bucket = (row>>4)*4 + (k>>5)   (16 buckets x 1KB)
//   slot   = ((k>>3)&3)*16 + (row&15)  == the MFMA lane that consumes it
//   j      = k&7 (contiguous 16B per lane -> one ds_read_b128)
// Slots XOR-swizzled by (bucket&7) to kill staging write conflicts.
__global__ __launch_bounds__(512) void triplet_one_k(const float* __restrict__ a,
                                                     const float* __restrict__ b,
                                                     float* __restrict__ partials,
                                                     unsigned int* __restrict__ cnt,
                                                     float* __restrict__ out) {
    __shared__ __align__(16) ushort A_s[16 * 512];  // 16 KB
    __shared__ __align__(16) ushort B_s[16 * 512];  // 16 KB
    __shared__ float ta_s[TILE], tb_s[TILE], dap_s[TILE];
    __shared__ float wsum_s[8];
    __shared__ int last_s;

    const int tid = threadIdx.x;
    const int bidx = (int)blockIdx.x, bidy = (int)blockIdx.y;
    const int j0 = bidy * TILE;
    const int k0 = bidx * TILE;

    // ---------- Phase 1: coalesced loads + exact-fp32 stats + bf16 staging ----
    const int r    = tid >> 3;  // 0..63 local row
    const int part = tid & 7;   // 64B segment within the 512B row
    const float4* pa  = reinterpret_cast<const float4*>(a + (size_t)(j0 + r) * DD + part * 16);
    const float4* pbj = reinterpret_cast<const float4*>(b + (size_t)(j0 + r) * DD + part * 16);
    const float4* pbk = reinterpret_cast<const float4*>(b + (size_t)(k0 + r) * DD + part * 16);

    F4 av[4], bjv[4], bkv[4];
#pragma unroll
    for (int i = 0; i < 4; ++i) av[i].v = pa[i];
#pragma unroll
    for (int i = 0; i < 4; ++i) bjv[i].v = pbj[i];
#pragma unroll
    for (int i = 0; i < 4; ++i) bkv[i].v = pbk[i];

    float sa2 = 0.f, sa = 0.f, sap = 0.f, sb2 = 0.f, sb = 0.f;
#pragma unroll
    for (int i = 0; i < 4; ++i)
#pragma unroll
        for (int c = 0; c < 4; ++c) {
            const float x = av[i].f[c], yj = bjv[i].f[c], yk = bkv[i].f[c];
            sa2 = fmaf(x, x, sa2);
            sa += x;
            const float d = x - yj + EPSF;
            sap = fmaf(d, d, sap);
            sb2 = fmaf(yk, yk, sb2);
            sb += yk;
        }
#pragma unroll
    for (int off = 1; off <= 4; off <<= 1) {  // reduce 8-lane row groups
        sa2 += __shfl_xor(sa2, off);
        sa  += __shfl_xor(sa,  off);
        sap += __shfl_xor(sap, off);
        sb2 += __shfl_xor(sb2, off);
        sb  += __shfl_xor(sb,  off);
    }
    if (part == 0) {
        ta_s[r]  = fmaf(2.f * EPSF, sa, sa2);
        tb_s[r]  = fmaf(-2.f * EPSF, sb, sb2);
        dap_s[r] = sqrtf(sap);
    }

    // staging: this thread's 16 a-elems (k = part*16..part*16+15) form exactly
    // two 8-elem lane-fragments of one bucket; same for bk.
    {
        const int bucket = (r >> 4) * 4 + (part >> 1);
        const int g = bucket & 7;
        const int slot0 = (part & 1) * 32 + (r & 15);  // lk0*16 + lr
        const int s0 = slot0 ^ g;
        const int s1 = (slot0 + 16) ^ g;
        bf16x8 w0, w1, x0, x1;
#pragma unroll
        for (int c = 0; c < 4; ++c) {
            w0[c] = f2bf(av[0].f[c]);  w0[4 + c] = f2bf(av[1].f[c]);
            w1[c] = f2bf(av[2].f[c]);  w1[4 + c] = f2bf(av[3].f[c]);
            x0[c] = f2bf(bkv[0].f[c]); x0[4 + c] = f2bf(bkv[1].f[c]);
            x1[c] = f2bf(bkv[2].f[c]); x1[4 + c] = f2bf(bkv[3].f[c]);
        }
        *reinterpret_cast<bf16x8*>(&A_s[bucket * 512 + s0 * 8]) = w0;
        *reinterpret_cast<bf16x8*>(&A_s[bucket * 512 + s1 * 8]) = w1;
        *reinterpret_cast<bf16x8*>(&B_s[bucket * 512 + s0 * 8]) = x0;
        *reinterpret_cast<bf16x8*>(&B_s[bucket * 512 + s1 * 8]) = x1;
    }
    __syncthreads();

    // ---------- Phase 2: MFMA over conflict-free lane-linear fragments -------
    const int w = tid >> 6, lane = tid & 63;
    const int wr = w >> 2;  // 0..1 : 32-row group
    const int wc = w & 3;   // 0..3 : 16-col group

    f32x4 acc0 = {0.f, 0.f, 0.f, 0.f}, acc1 = {0.f, 0.f, 0.f, 0.f};
#pragma unroll
    for (int kc = 0; kc < 4; ++kc) {
        const int bA0 = (2 * wr) * 4 + kc;
        const int bA1 = (2 * wr + 1) * 4 + kc;
        const int bB  = wc * 4 + kc;
        const bf16x8 fa0 = *reinterpret_cast<const bf16x8*>(&A_s[bA0 * 512 + (lane ^ (bA0 & 7)) * 8]);
        const bf16x8 fa1 = *reinterpret_cast<const bf16x8*>(&A_s[bA1 * 512 + (lane ^ (bA1 & 7)) * 8]);
        const bf16x8 fb  = *reinterpret_cast<const bf16x8*>(&B_s[bB * 512 + (lane ^ (bB & 7)) * 8]);
        acc0 = __builtin_amdgcn_mfma_f32_16x16x32_bf16(fa0, fb, acc0, 0, 0, 0);
        acc1 = __builtin_amdgcn_mfma_f32_16x16x32_bf16(fa1, fb, acc1, 0, 0, 0);
    }

    // ---------- Phase 3: fused epilogue ----------
    const float Ceps = (float)DD * EPSF * EPSF;
    const int colL = wc * 16 + (lane & 15);
    const int col  = k0 + colL;
    const float tb = tb_s[colL];
    float local = 0.f;
#pragma unroll
    for (int m = 0; m < 2; ++m) {
        const f32x4 acc = m ? acc1 : acc0;
#pragma unroll
        for (int reg = 0; reg < 4; ++reg) {
            const int rowL = wr * 32 + m * 16 + (lane >> 4) * 4 + reg;
            const int row  = j0 + rowL;
            const float d2 = ta_s[rowL] + tb + Ceps - 2.f * acc[reg];
            const float dn = sqrtf(fmaxf(d2, 0.f));
            if (row != col) local += fmaxf(dap_s[rowL] - dn + MARGINF, 0.f);
        }
    }

    // ---------- Phase 4: block reduce + last-block-done finalize ----------
#pragma unroll
    for (int off = 32; off >= 1; off >>= 1) local += __shfl_xor(local, off);
    if (lane == 0) wsum_s[w] = local;
    __syncthreads();
    if (tid == 0) {
        float s = 0.f;
#pragma unroll
        for (int i = 0; i < 8; ++i) s += wsum_s[i];
        partials[bidy * 16 + bidx] = s;
        __threadfence();  // publish partial before signaling
        const unsigned int old = atomicAdd(cnt, 1u);
        last_s = (((old + 1u) & (NBLK - 1u)) == 0u) ? 1 : 0;  // start-value independent
    }
    __syncthreads();
    if (last_s) {
        float v = 0.f;
        if (tid < NBLK) v = atomicAdd(&partials[tid], 0.0f);  // device-scope read
#pragma unroll
        for (int off = 32; off >= 1; off >>= 1) v += __shfl_xor(v, off);
        if ((tid & 63) == 0) wsum_s[tid >> 6] = v;
        __syncthreads();
        if (tid == 0) {
            float t = 0.f;
#pragma unroll
            for (int i = 0; i < 8; ++i) t += wsum_s[i];
            out[0] = t * INV_COUNT;
        }
    }
}

extern "C" void kernel_launch(void* const* d_in, const int* in_sizes, int n_in,
                              void* d_out, int out_size, void* d_ws, size_t ws_size,
                              hipStream_t stream) {
    const float* a = (const float*)d_in[0];
    const float* b = (const float*)d_in[1];
    float* partials   = (float*)d_ws;                 // 256 floats
    unsigned int* cnt = (unsigned int*)d_ws + NBLK;   // 1 uint, own cache line region
    float* out        = (float*)d_out;

    dim3 grid(BB / TILE, BB / TILE);
    triplet_one_k<<<grid, 512, 0, stream>>>(a, b, partials, cnt, out);
}